// Round 4
// baseline (465.386 us; speedup 1.0000x reference)
//
#include <hip/hip_runtime.h>
#include <hip/hip_bf16.h>

#define NNODES 50000
#define NEDGES 800000
#define F_IN 128
#define F_HID 256

using u16 = unsigned short;
using u32 = unsigned int;
using f32x4 = __attribute__((ext_vector_type(4))) float;
using s16x8 = __attribute__((ext_vector_type(8))) short;

constexpr int SCAN_BLOCKS = (NNODES + 255) / 256;  // 196
constexpr int BSHIFT = 5;                          // 32 nodes per bucket
constexpr int NBUCK = (NNODES + 31) >> 5;          // 1563

// ---------------- workspace layout (bytes) ----------------
constexpr size_t OFF_FLAG   = 0;          // 256
constexpr size_t OFF_DINV   = 256;        // 200192
constexpr size_t OFF_ROWPTR = 200448;     // 200192
constexpr size_t OFF_CNT    = 400640;     // 200192
constexpr size_t OFF_BSUM   = 600832;     // 1024
constexpr size_t OFF_BSUMS  = 601856;     // 1024
constexpr size_t OFF_BCUR   = 602880;     // 6400 (1563*4)
constexpr size_t OFF_PAIRS  = 609280;     // 3200000 (800000 u32)
constexpr size_t OFF_COL16  = 3809280;    // 1600000 (800000 u16)
constexpr size_t OFF_XB     = 5409280;    // 12800000 (50000x128 bf16)
constexpr size_t OFF_HB     = 18209280;   // 25600000 (50000x256 bf16)
constexpr size_t OFF_AGGB   = 43809280;   // 25600000
constexpr size_t OFF_W1T    = 69409280;   // 65536
constexpr size_t OFF_W2T    = 69474816;   // 131072
constexpr size_t OFF_W3T    = 69605888;   // 131072
// total ~69.7 MB

static __device__ __forceinline__ float b2f(u16 u) {
    union { unsigned int i; float f; } v;
    v.i = ((unsigned int)u) << 16;
    return v.f;
}
static __device__ __forceinline__ u16 f2b(float f) {
    __hip_bfloat16 h = __float2bfloat16(f);  // round-to-nearest
    return __builtin_bit_cast(u16, h);
}

// ---------------- edge dtype detect ----------------
__global__ void detect_kernel(const unsigned long long* __restrict__ p, int* __restrict__ flag) {
    __shared__ int bad;
    if (threadIdx.x == 0) bad = 0;
    __syncthreads();
    unsigned long long v = p[threadIdx.x];
    if (v >= (unsigned long long)NNODES) atomicAdd(&bad, 1);
    __syncthreads();
    if (threadIdx.x == 0) *flag = (bad == 0) ? 1 : 0;  // 1 => int64 layout
}

// ---------------- degree count (reads raw dst directly) ----------------
__global__ __launch_bounds__(256) void count_kernel(const void* __restrict__ raw,
                                                    const int* __restrict__ flag,
                                                    int* __restrict__ cnt) {
    int e = blockIdx.x * 256 + threadIdx.x;
    if (e >= NEDGES) return;
    int d;
    if (*flag) d = (int)((const long long*)raw)[NEDGES + e];
    else       d = ((const int*)raw)[NEDGES + e];
    atomicAdd(&cnt[d], 1);
}

// ---------------- exclusive scan (3 kernels); dinv fused into reduce; bcur fused into final ----------------
__global__ __launch_bounds__(256) void scan_reduce(const int* __restrict__ cnt, int* __restrict__ bsum,
                                                   float* __restrict__ dinv) {
    __shared__ int s[256];
    int i = blockIdx.x * 256 + threadIdx.x;
    int c = (i < NNODES) ? cnt[i] : 0;
    if (i < NNODES) dinv[i] = rsqrtf((float)c + 1.0f);  // +1 self-loop
    s[threadIdx.x] = c;
    __syncthreads();
    for (int o = 128; o > 0; o >>= 1) {
        if (threadIdx.x < o) s[threadIdx.x] += s[threadIdx.x + o];
        __syncthreads();
    }
    if (threadIdx.x == 0) bsum[blockIdx.x] = s[0];
}

__global__ __launch_bounds__(256) void scan_top(const int* __restrict__ bsum, int* __restrict__ bsumS) {
    __shared__ int s[256];
    int t = threadIdx.x;
    int v = (t < SCAN_BLOCKS) ? bsum[t] : 0;
    s[t] = v;
    __syncthreads();
    for (int o = 1; o < 256; o <<= 1) {
        int tmp = (t >= o) ? s[t - o] : 0;
        __syncthreads();
        s[t] += tmp;
        __syncthreads();
    }
    if (t < SCAN_BLOCKS) bsumS[t] = s[t] - v;
}

__global__ __launch_bounds__(256) void scan_final(const int* __restrict__ cnt, const int* __restrict__ bsumS,
                                                  int* __restrict__ row_ptr, int* __restrict__ bcur) {
    __shared__ int s[256];
    int t = threadIdx.x;
    int i = blockIdx.x * 256 + t;
    int v = (i < NNODES) ? cnt[i] : 0;
    s[t] = v;
    __syncthreads();
    for (int o = 1; o < 256; o <<= 1) {
        int tmp = (t >= o) ? s[t - o] : 0;
        __syncthreads();
        s[t] += tmp;
        __syncthreads();
    }
    if (i < NNODES) {
        int rp = s[t] - v + bsumS[blockIdx.x];
        row_ptr[i] = rp;
        if ((i & 31) == 0) bcur[i >> BSHIFT] = rp;  // bucket cursor init
    }
    if (i == 0) row_ptr[NNODES] = NEDGES;
}

// ---------------- phase 1: bin edges into exact CSR bucket regions ----------------
// pairs[pos] = (d&31)<<16 | src   (src < 50000 < 2^16)
__global__ __launch_bounds__(256) void phase1_bin(const void* __restrict__ raw,
                                                  const int* __restrict__ flag,
                                                  int* __restrict__ bcur, u32* __restrict__ pairs) {
    int e = blockIdx.x * 256 + threadIdx.x;
    if (e >= NEDGES) return;
    int s, d;
    if (*flag) {
        const long long* p = (const long long*)raw;
        s = (int)p[e];
        d = (int)p[NEDGES + e];
    } else {
        const int* p = (const int*)raw;
        s = p[e];
        d = p[NEDGES + e];
    }
    int pos = atomicAdd(&bcur[d >> BSHIFT], 1);
    pairs[pos] = ((u32)(d & 31) << 16) | (u32)s;
}

// ---------------- phase 2: per-bucket LDS ranking -> u16 col ----------------
__global__ __launch_bounds__(256) void phase2_fill(const u32* __restrict__ pairs,
                                                   const int* __restrict__ row_ptr,
                                                   u16* __restrict__ col) {
    __shared__ int lcnt[32];
    __shared__ int lbase[32];
    int b = blockIdx.x;
    int n0 = b << BSHIFT;
    int t = threadIdx.x;
    if (t < 32) {
        lcnt[t] = 0;
        int nd = n0 + t;
        lbase[t] = (nd < NNODES) ? row_ptr[nd] : NEDGES;
    }
    __syncthreads();
    int hi = n0 + 32; if (hi > NNODES) hi = NNODES;
    int p0 = row_ptr[n0];
    int p1 = row_ptr[hi];
    for (int p = p0 + t; p < p1; p += 256) {
        u32 pk = pairs[p];
        int dl = (int)(pk >> 16);
        int src = (int)(pk & 0xFFFFu);
        int r = atomicAdd(&lcnt[dl], 1);
        col[lbase[dl] + r] = (u16)src;
    }
}

// ---------------- fp32 -> bf16 converts ----------------
__global__ __launch_bounds__(256) void x2b_kernel(const float* __restrict__ x, u16* __restrict__ xb) {
    int i = blockIdx.x * 256 + threadIdx.x;  // over float4 units
    float4 v = ((const float4*)x)[i];
    ushort4 o;
    o.x = f2b(v.x); o.y = f2b(v.y); o.z = f2b(v.z); o.w = f2b(v.w);
    ((ushort4*)xb)[i] = o;
}

// all three weight transposes in one launch: W[K][256] -> Wt[256][K] bf16
__global__ __launch_bounds__(256) void wt_all(const float* __restrict__ W1, const float* __restrict__ W2,
                                              const float* __restrict__ W3, u16* __restrict__ W1t,
                                              u16* __restrict__ W2t, u16* __restrict__ W3t) {
    int idx = blockIdx.x * 256 + threadIdx.x;  // total 32768 + 65536 + 65536 = 163840
    if (idx < 32768) {
        int k = idx >> 8, n = idx & 255;
        W1t[n * 128 + k] = f2b(W1[idx]);
    } else if (idx < 98304) {
        int j = idx - 32768;
        int k = j >> 8, n = j & 255;
        W2t[n * 256 + k] = f2b(W2[j]);
    } else if (idx < 163840) {
        int j = idx - 98304;
        int k = j >> 8, n = j & 255;
        W3t[n * 256 + k] = f2b(W3[j]);
    }
}

// ---------------- aggregation ----------------
// out[v] = dv * ( dv*h[v] + sum_e dinv[col[e]] * h[col[e]] ),  dv = dinv[v]
template <int F>
__global__ __launch_bounds__(256) void agg_kernel(const u16* __restrict__ h,
                                                  const int* __restrict__ row_ptr,
                                                  const u16* __restrict__ col,
                                                  const float* __restrict__ dinv,
                                                  u16* __restrict__ outb) {
    constexpr int VEC = F / 64;  // 2 (F=128) or 4 (F=256) bf16 per lane
    int lane = threadIdx.x & 63;
    int v = __builtin_amdgcn_readfirstlane((int)(blockIdx.x * 4 + (threadIdx.x >> 6)));
    const size_t lo = (size_t)lane * VEC;

    float acc[VEC];
    float dv = dinv[v];
    {
        const u16* p = h + (size_t)v * F + lo;
        if constexpr (VEC == 4) {
            ushort4 t = *(const ushort4*)p;
            acc[0] = dv * b2f(t.x); acc[1] = dv * b2f(t.y); acc[2] = dv * b2f(t.z); acc[3] = dv * b2f(t.w);
        } else {
            ushort2 t = *(const ushort2*)p;
            acc[0] = dv * b2f(t.x); acc[1] = dv * b2f(t.y);
        }
    }
    const int e0 = row_ptr[v], e1 = row_ptr[v + 1];
    // unroll-8 with wave-uniform guards (e,e1 uniform): full groups issue 8 gathers in flight
    for (int e = e0; e < e1; e += 8) {
        int   c[8];
        float w[8];
#pragma unroll
        for (int u = 0; u < 8; ++u) {
            if (e + u < e1) {
                c[u] = (int)col[e + u];
                w[u] = dinv[c[u]];
            } else {
                c[u] = 0;
                w[u] = 0.0f;
            }
        }
        if constexpr (VEC == 4) {
            ushort4 r[8];
#pragma unroll
            for (int u = 0; u < 8; ++u)
                if (e + u < e1) r[u] = *(const ushort4*)(h + (size_t)c[u] * F + lo);
#pragma unroll
            for (int u = 0; u < 8; ++u) {
                if (e + u < e1) {
                    acc[0] += w[u] * b2f(r[u].x);
                    acc[1] += w[u] * b2f(r[u].y);
                    acc[2] += w[u] * b2f(r[u].z);
                    acc[3] += w[u] * b2f(r[u].w);
                }
            }
        } else {
            ushort2 r[8];
#pragma unroll
            for (int u = 0; u < 8; ++u)
                if (e + u < e1) r[u] = *(const ushort2*)(h + (size_t)c[u] * F + lo);
#pragma unroll
            for (int u = 0; u < 8; ++u) {
                if (e + u < e1) {
                    acc[0] += w[u] * b2f(r[u].x);
                    acc[1] += w[u] * b2f(r[u].y);
                }
            }
        }
    }
    u16* o = outb + (size_t)v * F + lo;
    if constexpr (VEC == 4) {
        ushort4 t;
        t.x = f2b(dv * acc[0]); t.y = f2b(dv * acc[1]); t.z = f2b(dv * acc[2]); t.w = f2b(dv * acc[3]);
        *(ushort4*)o = t;
    } else {
        ushort2 t;
        t.x = f2b(dv * acc[0]); t.y = f2b(dv * acc[1]);
        *(ushort2*)o = t;
    }
}

// ---------------- bf16 MFMA GEMM: out[M x 256] = A[M x KT] @ W[KT x 256] + b ----------------
template <int KT, bool RELU, bool OUT_BF16>
__global__ __launch_bounds__(256) void gemm_mfma(const u16* __restrict__ A, const u16* __restrict__ Wt,
                                                 const float* __restrict__ bias, void* __restrict__ outp,
                                                 int M) {
    constexpr int BM = 128, BN = 128, BK = 32;
    __shared__ __align__(16) u16 As[BM * BK];
    __shared__ __align__(16) u16 Bs[BN * BK];
    const int tid = threadIdx.x;
    const int lane = tid & 63, wid = tid >> 6;
    const int l15 = lane & 15, lhi = lane >> 4;
    const int m0 = blockIdx.x * BM, n0 = blockIdx.y * BN;
    const int wr = (wid >> 1) * 64, wc = (wid & 1) * 64;

    f32x4 acc[4][4] = {};

    const int sr = tid >> 1;        // staging row 0..127
    const int sc2 = (tid & 1) * 2;  // staging chunk base (0 or 2)

    for (int k0 = 0; k0 < KT; k0 += BK) {
        uint4 av0, av1, bv0, bv1;
        int ar = m0 + sr;
        if (ar < M) {
            const uint4* ap = (const uint4*)(A + (size_t)ar * KT + k0 + sc2 * 8);
            av0 = ap[0]; av1 = ap[1];
        } else {
            av0 = make_uint4(0, 0, 0, 0); av1 = av0;
        }
        const uint4* bp = (const uint4*)(Wt + (size_t)(n0 + sr) * KT + k0 + sc2 * 8);
        bv0 = bp[0]; bv1 = bp[1];

        __syncthreads();
        *(uint4*)&As[sr * BK + ((sc2 ^ (sr & 3)) * 8)]       = av0;
        *(uint4*)&As[sr * BK + (((sc2 + 1) ^ (sr & 3)) * 8)] = av1;
        *(uint4*)&Bs[sr * BK + ((sc2 ^ (sr & 3)) * 8)]       = bv0;
        *(uint4*)&Bs[sr * BK + (((sc2 + 1) ^ (sr & 3)) * 8)] = bv1;
        __syncthreads();

        s16x8 af[4], bfr[4];
#pragma unroll
        for (int m = 0; m < 4; ++m) {
            int r = wr + m * 16 + l15;
            af[m] = *(const s16x8*)&As[r * BK + ((lhi ^ (r & 3)) * 8)];
        }
#pragma unroll
        for (int n = 0; n < 4; ++n) {
            int r = wc + n * 16 + l15;
            bfr[n] = *(const s16x8*)&Bs[r * BK + ((lhi ^ (r & 3)) * 8)];
        }
#pragma unroll
        for (int m = 0; m < 4; ++m)
#pragma unroll
            for (int n = 0; n < 4; ++n)
                acc[m][n] = __builtin_amdgcn_mfma_f32_16x16x32_bf16(af[m], bfr[n], acc[m][n], 0, 0, 0);
    }

    // epilogue: C/D layout col = lane&15, row = (lane>>4)*4 + reg
#pragma unroll
    for (int n = 0; n < 4; ++n) {
        int gcol = n0 + wc + n * 16 + l15;
        float bb = bias[gcol];
#pragma unroll
        for (int m = 0; m < 4; ++m) {
            int gr0 = m0 + wr + m * 16 + lhi * 4;
#pragma unroll
            for (int r = 0; r < 4; ++r) {
                int gr = gr0 + r;
                if (gr >= M) continue;
                float vv = acc[m][n][r] + bb;
                if (RELU) vv = vv > 0.f ? vv : 0.f;
                if (OUT_BF16)
                    ((u16*)outp)[(size_t)gr * 256 + gcol] = f2b(vv);
                else
                    ((float*)outp)[(size_t)gr * 256 + gcol] = vv;
            }
        }
    }
}

// ---------------- launch ----------------
extern "C" void kernel_launch(void* const* d_in, const int* in_sizes, int n_in,
                              void* d_out, int out_size, void* d_ws, size_t ws_size,
                              hipStream_t stream) {
    const float* x  = (const float*)d_in[0];
    const void* edges = d_in[1];
    const float* W1 = (const float*)d_in[2];
    const float* b1 = (const float*)d_in[3];
    const float* W2 = (const float*)d_in[4];
    const float* b2 = (const float*)d_in[5];
    const float* W3 = (const float*)d_in[6];
    const float* b3 = (const float*)d_in[7];
    float* out = (float*)d_out;

    char* ws = (char*)d_ws;
    int*   flag   = (int*)(ws + OFF_FLAG);
    float* dinv   = (float*)(ws + OFF_DINV);
    int*   rowptr = (int*)(ws + OFF_ROWPTR);
    int*   cnt    = (int*)(ws + OFF_CNT);
    int*   bsum   = (int*)(ws + OFF_BSUM);
    int*   bsumS  = (int*)(ws + OFF_BSUMS);
    int*   bcur   = (int*)(ws + OFF_BCUR);
    u32*   pairs  = (u32*)(ws + OFF_PAIRS);
    u16*   col16  = (u16*)(ws + OFF_COL16);
    u16*   xb     = (u16*)(ws + OFF_XB);
    u16*   hb     = (u16*)(ws + OFF_HB);
    u16*   aggb   = (u16*)(ws + OFF_AGGB);
    u16*   W1t    = (u16*)(ws + OFF_W1T);
    u16*   W2t    = (u16*)(ws + OFF_W2T);
    u16*   W3t    = (u16*)(ws + OFF_W3T);

    const int EB = (NEDGES + 255) / 256;  // 3125

    hipMemsetAsync(cnt, 0, NNODES * sizeof(int), stream);
    detect_kernel<<<1, 256, 0, stream>>>((const unsigned long long*)edges, flag);
    count_kernel<<<EB, 256, 0, stream>>>(edges, flag, cnt);

    // exclusive scan -> row_ptr (+dinv, +bucket cursors)
    scan_reduce<<<SCAN_BLOCKS, 256, 0, stream>>>(cnt, bsum, dinv);
    scan_top<<<1, 256, 0, stream>>>(bsum, bsumS);
    scan_final<<<SCAN_BLOCKS, 256, 0, stream>>>(cnt, bsumS, rowptr, bcur);

    // bucketed CSR build
    phase1_bin<<<EB, 256, 0, stream>>>(edges, flag, bcur, pairs);
    phase2_fill<<<NBUCK, 256, 0, stream>>>(pairs, rowptr, col16);

    // bf16 converts
    x2b_kernel<<<(NNODES * F_IN / 4 + 255) / 256, 256, 0, stream>>>(x, xb);
    wt_all<<<640, 256, 0, stream>>>(W1, W2, W3, W1t, W2t, W3t);

    const int AGG_GRID = NNODES / 4;  // 12500
    dim3 ggrid((NNODES + 127) / 128, 2);

    // layer 1
    agg_kernel<F_IN><<<AGG_GRID, 256, 0, stream>>>(xb, rowptr, col16, dinv, aggb);
    gemm_mfma<F_IN, true, true><<<ggrid, 256, 0, stream>>>(aggb, W1t, b1, hb, NNODES);

    // layer 2
    agg_kernel<F_HID><<<AGG_GRID, 256, 0, stream>>>(hb, rowptr, col16, dinv, aggb);
    gemm_mfma<F_HID, true, true><<<ggrid, 256, 0, stream>>>(aggb, W2t, b2, hb, NNODES);

    // layer 3
    agg_kernel<F_HID><<<AGG_GRID, 256, 0, stream>>>(hb, rowptr, col16, dinv, aggb);
    gemm_mfma<F_HID, false, false><<<ggrid, 256, 0, stream>>>(aggb, W3t, b3, out, NNODES);
}

// Round 5
// 364.305 us; speedup vs baseline: 1.2775x; 1.2775x over previous
//
#include <hip/hip_runtime.h>
#include <hip/hip_bf16.h>

#define NNODES 50000
#define NEDGES 800000
#define F_IN 128
#define F_HID 256

using u16 = unsigned short;
using u32 = unsigned int;
using f32x4 = __attribute__((ext_vector_type(4))) float;
using s16x8 = __attribute__((ext_vector_type(8))) short;

constexpr int SCAN_BLOCKS = (NNODES + 255) / 256;  // 196
constexpr int B2SHIFT = 9;                         // 512 nodes per coarse bucket
constexpr int NB2 = (NNODES + 511) >> 9;           // 98
constexpr int NBLK = 256;                          // scatter blocks
constexpr int EPB = NEDGES / NBLK;                 // 3125 edges per block (exact)

// ---------------- workspace layout (bytes) ----------------
constexpr size_t OFF_FLAG   = 0;          // 256
constexpr size_t OFF_DINV   = 256;        // 200192
constexpr size_t OFF_ROWPTR = 200448;     // 200192
constexpr size_t OFF_CNT    = 400640;     // 200192
constexpr size_t OFF_BSUM   = 600832;     // 1024
constexpr size_t OFF_BSUMS  = 601856;     // 1024
constexpr size_t OFF_CMAT   = 602880;     // 100352 (98*256*4)
constexpr size_t OFF_PAIRS  = 703232;     // 3200000 (800000 u32)
constexpr size_t OFF_COL16  = 3903232;    // 1600000 (800000 u16)
constexpr size_t OFF_XB     = 5503232;    // 12800000 (50000x128 bf16)
constexpr size_t OFF_HB     = 18303232;   // 25600000 (50000x256 bf16)
constexpr size_t OFF_AGGB   = 43903232;   // 25600000
constexpr size_t OFF_W1T    = 69503232;   // 65536
constexpr size_t OFF_W2T    = 69568768;   // 131072
constexpr size_t OFF_W3T    = 69699840;   // 131072
// total ~69.8 MB

static __device__ __forceinline__ float b2f(u16 u) {
    union { unsigned int i; float f; } v;
    v.i = ((unsigned int)u) << 16;
    return v.f;
}
static __device__ __forceinline__ u16 f2b(float f) {
    __hip_bfloat16 h = __float2bfloat16(f);  // round-to-nearest
    return __builtin_bit_cast(u16, h);
}

// ---------------- edge dtype detect ----------------
__global__ void detect_kernel(const unsigned long long* __restrict__ p, int* __restrict__ flag) {
    __shared__ int bad;
    if (threadIdx.x == 0) bad = 0;
    __syncthreads();
    unsigned long long v = p[threadIdx.x];
    if (v >= (unsigned long long)NNODES) atomicAdd(&bad, 1);
    __syncthreads();
    if (threadIdx.x == 0) *flag = (bad == 0) ? 1 : 0;  // 1 => int64 layout
}

// ---------------- CSR build, contention-free ----------------
// A: per-block LDS histogram over 98 coarse buckets (+ fused degree count)
__global__ __launch_bounds__(256) void hist_kernel(const void* __restrict__ raw,
                                                   const int* __restrict__ flag,
                                                   int* __restrict__ cnt, int* __restrict__ cmat) {
    __shared__ int h[NB2];
    int t = threadIdx.x;
    if (t < NB2) h[t] = 0;
    __syncthreads();
    const int base = blockIdx.x * EPB;
    const bool wide = (*flag != 0);
    for (int i = t; i < EPB; i += 256) {
        int e = base + i;
        int d = wide ? (int)((const long long*)raw)[NEDGES + e] : ((const int*)raw)[NEDGES + e];
        atomicAdd(&h[d >> B2SHIFT], 1);
        atomicAdd(&cnt[d], 1);  // degree (16 avg per address — cheap)
    }
    __syncthreads();
    if (t < NB2) cmat[t * NBLK + blockIdx.x] = h[t];
}

// B: per-bucket exclusive scan over the 256 block-counts, based at row_ptr[bucket_start]
__global__ __launch_bounds__(256) void offset_kernel(const int* __restrict__ row_ptr, int* __restrict__ cmat) {
    __shared__ int s[256];
    int b = blockIdx.x;      // bucket
    int t = threadIdx.x;     // block slot
    int v = cmat[b * NBLK + t];
    s[t] = v;
    __syncthreads();
    for (int o = 1; o < 256; o <<= 1) {
        int tmp = (t >= o) ? s[t - o] : 0;
        __syncthreads();
        s[t] += tmp;
        __syncthreads();
    }
    cmat[b * NBLK + t] = row_ptr[b << B2SHIFT] + s[t] - v;  // exclusive + bucket base
}

// C: scatter edges into exact CSR bucket regions; cursors live in LDS (block-private)
__global__ __launch_bounds__(256) void scatter_kernel(const void* __restrict__ raw,
                                                      const int* __restrict__ flag,
                                                      const int* __restrict__ cmat,
                                                      u32* __restrict__ pairs) {
    __shared__ int cur[NB2];
    int t = threadIdx.x;
    if (t < NB2) cur[t] = cmat[t * NBLK + blockIdx.x];
    __syncthreads();
    const int base = blockIdx.x * EPB;
    const bool wide = (*flag != 0);
    for (int i = t; i < EPB; i += 256) {
        int e = base + i;
        int s, d;
        if (wide) {
            const long long* p = (const long long*)raw;
            s = (int)p[e];
            d = (int)p[NEDGES + e];
        } else {
            const int* p = (const int*)raw;
            s = p[e];
            d = p[NEDGES + e];
        }
        int pos = atomicAdd(&cur[d >> B2SHIFT], 1);
        pairs[pos] = ((u32)(d & 511) << 16) | (u32)s;  // src < 50000 < 2^16
    }
}

// D: per-bucket LDS ranking -> u16 col (block-exclusive 16KB write window)
__global__ __launch_bounds__(256) void phase2_fill(const u32* __restrict__ pairs,
                                                   const int* __restrict__ row_ptr,
                                                   u16* __restrict__ col) {
    __shared__ int lcnt[512];
    __shared__ int lbase[512];
    int b = blockIdx.x;
    int n0 = b << B2SHIFT;
    int t = threadIdx.x;
    for (int i = t; i < 512; i += 256) {
        lcnt[i] = 0;
        int nd = n0 + i;
        lbase[i] = (nd < NNODES) ? row_ptr[nd] : NEDGES;
    }
    __syncthreads();
    int hi = n0 + 512; if (hi > NNODES) hi = NNODES;
    int p0 = row_ptr[n0];
    int p1 = row_ptr[hi];
    for (int p = p0 + t; p < p1; p += 256) {
        u32 pk = pairs[p];
        int dl = (int)(pk >> 16);
        int r = atomicAdd(&lcnt[dl], 1);
        col[lbase[dl] + r] = (u16)(pk & 0xFFFFu);
    }
}

// ---------------- exclusive scan for row_ptr (dinv fused) ----------------
__global__ __launch_bounds__(256) void scan_reduce(const int* __restrict__ cnt, int* __restrict__ bsum,
                                                   float* __restrict__ dinv) {
    __shared__ int s[256];
    int i = blockIdx.x * 256 + threadIdx.x;
    int c = (i < NNODES) ? cnt[i] : 0;
    if (i < NNODES) dinv[i] = rsqrtf((float)c + 1.0f);  // +1 self-loop
    s[threadIdx.x] = c;
    __syncthreads();
    for (int o = 128; o > 0; o >>= 1) {
        if (threadIdx.x < o) s[threadIdx.x] += s[threadIdx.x + o];
        __syncthreads();
    }
    if (threadIdx.x == 0) bsum[blockIdx.x] = s[0];
}

__global__ __launch_bounds__(256) void scan_top(const int* __restrict__ bsum, int* __restrict__ bsumS) {
    __shared__ int s[256];
    int t = threadIdx.x;
    int v = (t < SCAN_BLOCKS) ? bsum[t] : 0;
    s[t] = v;
    __syncthreads();
    for (int o = 1; o < 256; o <<= 1) {
        int tmp = (t >= o) ? s[t - o] : 0;
        __syncthreads();
        s[t] += tmp;
        __syncthreads();
    }
    if (t < SCAN_BLOCKS) bsumS[t] = s[t] - v;
}

__global__ __launch_bounds__(256) void scan_final(const int* __restrict__ cnt, const int* __restrict__ bsumS,
                                                  int* __restrict__ row_ptr) {
    __shared__ int s[256];
    int t = threadIdx.x;
    int i = blockIdx.x * 256 + t;
    int v = (i < NNODES) ? cnt[i] : 0;
    s[t] = v;
    __syncthreads();
    for (int o = 1; o < 256; o <<= 1) {
        int tmp = (t >= o) ? s[t - o] : 0;
        __syncthreads();
        s[t] += tmp;
        __syncthreads();
    }
    if (i < NNODES) row_ptr[i] = s[t] - v + bsumS[blockIdx.x];
    if (i == 0) row_ptr[NNODES] = NEDGES;
}

// ---------------- fp32 -> bf16 converts ----------------
__global__ __launch_bounds__(256) void x2b_kernel(const float* __restrict__ x, u16* __restrict__ xb) {
    int i = blockIdx.x * 256 + threadIdx.x;  // over float4 units
    float4 v = ((const float4*)x)[i];
    ushort4 o;
    o.x = f2b(v.x); o.y = f2b(v.y); o.z = f2b(v.z); o.w = f2b(v.w);
    ((ushort4*)xb)[i] = o;
}

// all three weight transposes in one launch: W[K][256] -> Wt[256][K] bf16
__global__ __launch_bounds__(256) void wt_all(const float* __restrict__ W1, const float* __restrict__ W2,
                                              const float* __restrict__ W3, u16* __restrict__ W1t,
                                              u16* __restrict__ W2t, u16* __restrict__ W3t) {
    int idx = blockIdx.x * 256 + threadIdx.x;  // total 32768 + 65536 + 65536 = 163840
    if (idx < 32768) {
        int k = idx >> 8, n = idx & 255;
        W1t[n * 128 + k] = f2b(W1[idx]);
    } else if (idx < 98304) {
        int j = idx - 32768;
        int k = j >> 8, n = j & 255;
        W2t[n * 256 + k] = f2b(W2[j]);
    } else if (idx < 163840) {
        int j = idx - 98304;
        int k = j >> 8, n = j & 255;
        W3t[n * 256 + k] = f2b(W3[j]);
    }
}

// ---------------- aggregation ----------------
// out[v] = dv * ( dv*h[v] + sum_e dinv[col[e]] * h[col[e]] ),  dv = dinv[v]
template <int F>
__global__ __launch_bounds__(256) void agg_kernel(const u16* __restrict__ h,
                                                  const int* __restrict__ row_ptr,
                                                  const u16* __restrict__ col,
                                                  const float* __restrict__ dinv,
                                                  u16* __restrict__ outb) {
    constexpr int VEC = F / 64;  // 2 (F=128) or 4 (F=256) bf16 per lane
    int lane = threadIdx.x & 63;
    int v = __builtin_amdgcn_readfirstlane((int)(blockIdx.x * 4 + (threadIdx.x >> 6)));
    const size_t lo = (size_t)lane * VEC;

    float acc[VEC];
    float dv = dinv[v];
    {
        const u16* p = h + (size_t)v * F + lo;
        if constexpr (VEC == 4) {
            ushort4 t = *(const ushort4*)p;
            acc[0] = dv * b2f(t.x); acc[1] = dv * b2f(t.y); acc[2] = dv * b2f(t.z); acc[3] = dv * b2f(t.w);
        } else {
            ushort2 t = *(const ushort2*)p;
            acc[0] = dv * b2f(t.x); acc[1] = dv * b2f(t.y);
        }
    }
    const int e0 = row_ptr[v], e1 = row_ptr[v + 1];
    for (int e = e0; e < e1; e += 8) {
        int   c[8];
        float w[8];
#pragma unroll
        for (int u = 0; u < 8; ++u) {
            if (e + u < e1) {
                c[u] = (int)col[e + u];
                w[u] = dinv[c[u]];
            } else {
                c[u] = 0;
                w[u] = 0.0f;
            }
        }
        if constexpr (VEC == 4) {
            ushort4 r[8];
#pragma unroll
            for (int u = 0; u < 8; ++u)
                if (e + u < e1) r[u] = *(const ushort4*)(h + (size_t)c[u] * F + lo);
#pragma unroll
            for (int u = 0; u < 8; ++u) {
                if (e + u < e1) {
                    acc[0] += w[u] * b2f(r[u].x);
                    acc[1] += w[u] * b2f(r[u].y);
                    acc[2] += w[u] * b2f(r[u].z);
                    acc[3] += w[u] * b2f(r[u].w);
                }
            }
        } else {
            ushort2 r[8];
#pragma unroll
            for (int u = 0; u < 8; ++u)
                if (e + u < e1) r[u] = *(const ushort2*)(h + (size_t)c[u] * F + lo);
#pragma unroll
            for (int u = 0; u < 8; ++u) {
                if (e + u < e1) {
                    acc[0] += w[u] * b2f(r[u].x);
                    acc[1] += w[u] * b2f(r[u].y);
                }
            }
        }
    }
    u16* o = outb + (size_t)v * F + lo;
    if constexpr (VEC == 4) {
        ushort4 t;
        t.x = f2b(dv * acc[0]); t.y = f2b(dv * acc[1]); t.z = f2b(dv * acc[2]); t.w = f2b(dv * acc[3]);
        *(ushort4*)o = t;
    } else {
        ushort2 t;
        t.x = f2b(dv * acc[0]); t.y = f2b(dv * acc[1]);
        *(ushort2*)o = t;
    }
}

// ---------------- bf16 MFMA GEMM: out[M x 256] = A[M x KT] @ W[KT x 256] + b ----------------
template <int KT, bool RELU, bool OUT_BF16>
__global__ __launch_bounds__(256) void gemm_mfma(const u16* __restrict__ A, const u16* __restrict__ Wt,
                                                 const float* __restrict__ bias, void* __restrict__ outp,
                                                 int M) {
    constexpr int BM = 128, BN = 128, BK = 32;
    __shared__ __align__(16) u16 As[BM * BK];
    __shared__ __align__(16) u16 Bs[BN * BK];
    const int tid = threadIdx.x;
    const int lane = tid & 63, wid = tid >> 6;
    const int l15 = lane & 15, lhi = lane >> 4;
    const int m0 = blockIdx.x * BM, n0 = blockIdx.y * BN;
    const int wr = (wid >> 1) * 64, wc = (wid & 1) * 64;

    f32x4 acc[4][4] = {};

    const int sr = tid >> 1;        // staging row 0..127
    const int sc2 = (tid & 1) * 2;  // staging chunk base (0 or 2)

    for (int k0 = 0; k0 < KT; k0 += BK) {
        uint4 av0, av1, bv0, bv1;
        int ar = m0 + sr;
        if (ar < M) {
            const uint4* ap = (const uint4*)(A + (size_t)ar * KT + k0 + sc2 * 8);
            av0 = ap[0]; av1 = ap[1];
        } else {
            av0 = make_uint4(0, 0, 0, 0); av1 = av0;
        }
        const uint4* bp = (const uint4*)(Wt + (size_t)(n0 + sr) * KT + k0 + sc2 * 8);
        bv0 = bp[0]; bv1 = bp[1];

        __syncthreads();
        *(uint4*)&As[sr * BK + ((sc2 ^ (sr & 3)) * 8)]       = av0;
        *(uint4*)&As[sr * BK + (((sc2 + 1) ^ (sr & 3)) * 8)] = av1;
        *(uint4*)&Bs[sr * BK + ((sc2 ^ (sr & 3)) * 8)]       = bv0;
        *(uint4*)&Bs[sr * BK + (((sc2 + 1) ^ (sr & 3)) * 8)] = bv1;
        __syncthreads();

        s16x8 af[4], bfr[4];
#pragma unroll
        for (int m = 0; m < 4; ++m) {
            int r = wr + m * 16 + l15;
            af[m] = *(const s16x8*)&As[r * BK + ((lhi ^ (r & 3)) * 8)];
        }
#pragma unroll
        for (int n = 0; n < 4; ++n) {
            int r = wc + n * 16 + l15;
            bfr[n] = *(const s16x8*)&Bs[r * BK + ((lhi ^ (r & 3)) * 8)];
        }
#pragma unroll
        for (int m = 0; m < 4; ++m)
#pragma unroll
            for (int n = 0; n < 4; ++n)
                acc[m][n] = __builtin_amdgcn_mfma_f32_16x16x32_bf16(af[m], bfr[n], acc[m][n], 0, 0, 0);
    }

    // epilogue: C/D layout col = lane&15, row = (lane>>4)*4 + reg
#pragma unroll
    for (int n = 0; n < 4; ++n) {
        int gcol = n0 + wc + n * 16 + l15;
        float bb = bias[gcol];
#pragma unroll
        for (int m = 0; m < 4; ++m) {
            int gr0 = m0 + wr + m * 16 + lhi * 4;
#pragma unroll
            for (int r = 0; r < 4; ++r) {
                int gr = gr0 + r;
                if (gr >= M) continue;
                float vv = acc[m][n][r] + bb;
                if (RELU) vv = vv > 0.f ? vv : 0.f;
                if (OUT_BF16)
                    ((u16*)outp)[(size_t)gr * 256 + gcol] = f2b(vv);
                else
                    ((float*)outp)[(size_t)gr * 256 + gcol] = vv;
            }
        }
    }
}

// ---------------- launch ----------------
extern "C" void kernel_launch(void* const* d_in, const int* in_sizes, int n_in,
                              void* d_out, int out_size, void* d_ws, size_t ws_size,
                              hipStream_t stream) {
    const float* x  = (const float*)d_in[0];
    const void* edges = d_in[1];
    const float* W1 = (const float*)d_in[2];
    const float* b1 = (const float*)d_in[3];
    const float* W2 = (const float*)d_in[4];
    const float* b2 = (const float*)d_in[5];
    const float* W3 = (const float*)d_in[6];
    const float* b3 = (const float*)d_in[7];
    float* out = (float*)d_out;

    char* ws = (char*)d_ws;
    int*   flag   = (int*)(ws + OFF_FLAG);
    float* dinv   = (float*)(ws + OFF_DINV);
    int*   rowptr = (int*)(ws + OFF_ROWPTR);
    int*   cnt    = (int*)(ws + OFF_CNT);
    int*   bsum   = (int*)(ws + OFF_BSUM);
    int*   bsumS  = (int*)(ws + OFF_BSUMS);
    int*   cmat   = (int*)(ws + OFF_CMAT);
    u32*   pairs  = (u32*)(ws + OFF_PAIRS);
    u16*   col16  = (u16*)(ws + OFF_COL16);
    u16*   xb     = (u16*)(ws + OFF_XB);
    u16*   hb     = (u16*)(ws + OFF_HB);
    u16*   aggb   = (u16*)(ws + OFF_AGGB);
    u16*   W1t    = (u16*)(ws + OFF_W1T);
    u16*   W2t    = (u16*)(ws + OFF_W2T);
    u16*   W3t    = (u16*)(ws + OFF_W3T);

    hipMemsetAsync(cnt, 0, NNODES * sizeof(int), stream);
    detect_kernel<<<1, 256, 0, stream>>>((const unsigned long long*)edges, flag);

    // histogram + degree count (fused)
    hist_kernel<<<NBLK, 256, 0, stream>>>(edges, flag, cnt, cmat);

    // exclusive scan -> row_ptr (+dinv)
    scan_reduce<<<SCAN_BLOCKS, 256, 0, stream>>>(cnt, bsum, dinv);
    scan_top<<<1, 256, 0, stream>>>(bsum, bsumS);
    scan_final<<<SCAN_BLOCKS, 256, 0, stream>>>(cnt, bsumS, rowptr);

    // per-(bucket,block) offsets; scatter; per-node ranking
    offset_kernel<<<NB2, 256, 0, stream>>>(rowptr, cmat);
    scatter_kernel<<<NBLK, 256, 0, stream>>>(edges, flag, cmat, pairs);
    phase2_fill<<<NB2, 256, 0, stream>>>(pairs, rowptr, col16);

    // bf16 converts
    x2b_kernel<<<(NNODES * F_IN / 4 + 255) / 256, 256, 0, stream>>>(x, xb);
    wt_all<<<640, 256, 0, stream>>>(W1, W2, W3, W1t, W2t, W3t);

    const int AGG_GRID = NNODES / 4;  // 12500
    dim3 ggrid((NNODES + 127) / 128, 2);

    // layer 1
    agg_kernel<F_IN><<<AGG_GRID, 256, 0, stream>>>(xb, rowptr, col16, dinv, aggb);
    gemm_mfma<F_IN, true, true><<<ggrid, 256, 0, stream>>>(aggb, W1t, b1, hb, NNODES);

    // layer 2
    agg_kernel<F_HID><<<AGG_GRID, 256, 0, stream>>>(hb, rowptr, col16, dinv, aggb);
    gemm_mfma<F_HID, true, true><<<ggrid, 256, 0, stream>>>(aggb, W2t, b2, hb, NNODES);

    // layer 3
    agg_kernel<F_HID><<<AGG_GRID, 256, 0, stream>>>(hb, rowptr, col16, dinv, aggb);
    gemm_mfma<F_HID, false, false><<<ggrid, 256, 0, stream>>>(aggb, W3t, b3, out, NNODES);
}

// Round 6
// 316.468 us; speedup vs baseline: 1.4706x; 1.1512x over previous
//
#include <hip/hip_runtime.h>
#include <hip/hip_bf16.h>

#define NNODES 50000
#define NEDGES 800000
#define F_IN 128
#define F_HID 256

using u16 = unsigned short;
using u32 = unsigned int;
using f32x4 = __attribute__((ext_vector_type(4))) float;
using s16x8 = __attribute__((ext_vector_type(8))) short;

constexpr int SCAN_BLOCKS = (NNODES + 255) / 256;  // 196
constexpr int B2SHIFT = 9;                         // 512 nodes per coarse bucket
constexpr int NB2 = (NNODES + 511) >> 9;           // 98
constexpr int NBLK = 256;                          // scatter blocks
constexpr int EPB = NEDGES / NBLK;                 // 3125 edges per block (exact)

// ---------------- workspace layout (bytes) ----------------
constexpr size_t OFF_DINV   = 0;          // 200192
constexpr size_t OFF_ROWPTR = 200192;     // 200192
constexpr size_t OFF_CNT    = 400384;     // 200192
constexpr size_t OFF_BSUM   = 600576;     // 1024
constexpr size_t OFF_BSUMS  = 601600;     // 1024
constexpr size_t OFF_CMAT   = 602624;     // 100352 (98*256*4)
constexpr size_t OFF_PAIRS  = 702976;     // 3200000 (800000 u32)
constexpr size_t OFF_PW     = 3902976;    // 3200000 (800000 u32 packed w|src)
constexpr size_t OFF_XB     = 7102976;    // 12800000 (50000x128 bf16)
constexpr size_t OFF_HB     = 19902976;   // 25600000 (50000x256 bf16)
constexpr size_t OFF_AGGB   = 45502976;   // 25600000
constexpr size_t OFF_W1T    = 71102976;   // 65536
constexpr size_t OFF_W2T    = 71168512;   // 131072
constexpr size_t OFF_W3T    = 71299584;   // 131072
// total ~71.4 MB

static __device__ __forceinline__ float b2f(u16 u) {
    union { unsigned int i; float f; } v;
    v.i = ((unsigned int)u) << 16;
    return v.f;
}
static __device__ __forceinline__ u16 f2b(float f) {
    __hip_bfloat16 h = __float2bfloat16(f);  // round-to-nearest
    return __builtin_bit_cast(u16, h);
}

// per-block edge-dtype detect: true => int64 layout.
// Reads first 256 u64 of the src row (L2-hot, 2KB). For int32 data the odds
// that all 256 upper halves are zero is (1/50000)^256 ~ 0.
static __device__ __forceinline__ bool detect_wide(const void* raw) {
    __shared__ int bad;
    if (threadIdx.x == 0) bad = 0;
    __syncthreads();
    unsigned long long v = ((const unsigned long long*)raw)[threadIdx.x & 255];
    if (v >= (unsigned long long)NNODES) atomicAdd(&bad, 1);
    __syncthreads();
    return bad == 0;
}

// ---------------- CSR build, contention-free ----------------
// A: per-block LDS histogram over 98 coarse buckets (+ fused degree count)
__global__ __launch_bounds__(256) void hist_kernel(const void* __restrict__ raw,
                                                   int* __restrict__ cnt, int* __restrict__ cmat) {
    const bool wide = detect_wide(raw);
    __shared__ int h[NB2];
    int t = threadIdx.x;
    if (t < NB2) h[t] = 0;
    __syncthreads();
    const int base = blockIdx.x * EPB;
    for (int i = t; i < EPB; i += 256) {
        int e = base + i;
        int d = wide ? (int)((const long long*)raw)[NEDGES + e] : ((const int*)raw)[NEDGES + e];
        atomicAdd(&h[d >> B2SHIFT], 1);
        atomicAdd(&cnt[d], 1);  // degree (16 avg per address — cheap)
    }
    __syncthreads();
    if (t < NB2) cmat[t * NBLK + blockIdx.x] = h[t];
}

// B: per-bucket exclusive scan over the 256 block-counts, based at row_ptr[bucket_start]
__global__ __launch_bounds__(256) void offset_kernel(const int* __restrict__ row_ptr, int* __restrict__ cmat) {
    __shared__ int s[256];
    int b = blockIdx.x;      // bucket
    int t = threadIdx.x;     // block slot
    int v = cmat[b * NBLK + t];
    s[t] = v;
    __syncthreads();
    for (int o = 1; o < 256; o <<= 1) {
        int tmp = (t >= o) ? s[t - o] : 0;
        __syncthreads();
        s[t] += tmp;
        __syncthreads();
    }
    cmat[b * NBLK + t] = row_ptr[b << B2SHIFT] + s[t] - v;  // exclusive + bucket base
}

// C: scatter edges into exact CSR bucket regions; cursors live in LDS (block-private)
__global__ __launch_bounds__(256) void scatter_kernel(const void* __restrict__ raw,
                                                      const int* __restrict__ cmat,
                                                      u32* __restrict__ pairs) {
    const bool wide = detect_wide(raw);
    __shared__ int cur[NB2];
    int t = threadIdx.x;
    if (t < NB2) cur[t] = cmat[t * NBLK + blockIdx.x];
    __syncthreads();
    const int base = blockIdx.x * EPB;
    for (int i = t; i < EPB; i += 256) {
        int e = base + i;
        int s, d;
        if (wide) {
            const long long* p = (const long long*)raw;
            s = (int)p[e];
            d = (int)p[NEDGES + e];
        } else {
            const int* p = (const int*)raw;
            s = p[e];
            d = p[NEDGES + e];
        }
        int pos = atomicAdd(&cur[d >> B2SHIFT], 1);
        pairs[pos] = ((u32)(d & 511) << 16) | (u32)s;  // src < 50000 < 2^16
    }
}

// D: per-bucket LDS ranking -> packed (bf16(dinv[src])<<16 | src) stream
__global__ __launch_bounds__(256) void phase2_fill(const u32* __restrict__ pairs,
                                                   const int* __restrict__ row_ptr,
                                                   const float* __restrict__ dinv,
                                                   u32* __restrict__ pw) {
    __shared__ int lcnt[512];
    __shared__ int lbase[512];
    int b = blockIdx.x;
    int n0 = b << B2SHIFT;
    int t = threadIdx.x;
    for (int i = t; i < 512; i += 256) {
        lcnt[i] = 0;
        int nd = n0 + i;
        lbase[i] = (nd < NNODES) ? row_ptr[nd] : NEDGES;
    }
    __syncthreads();
    int hi = n0 + 512; if (hi > NNODES) hi = NNODES;
    int p0 = row_ptr[n0];
    int p1 = row_ptr[hi];
    for (int p = p0 + t; p < p1; p += 256) {
        u32 pk = pairs[p];
        int dl = (int)(pk >> 16);
        int src = (int)(pk & 0xFFFFu);
        int r = atomicAdd(&lcnt[dl], 1);
        u16 wb = f2b(dinv[src]);  // dinv L2-resident (200KB)
        pw[lbase[dl] + r] = ((u32)wb << 16) | (u32)src;
    }
}

// ---------------- exclusive scan for row_ptr (dinv fused) ----------------
__global__ __launch_bounds__(256) void scan_reduce(const int* __restrict__ cnt, int* __restrict__ bsum,
                                                   float* __restrict__ dinv) {
    __shared__ int s[256];
    int i = blockIdx.x * 256 + threadIdx.x;
    int c = (i < NNODES) ? cnt[i] : 0;
    if (i < NNODES) dinv[i] = rsqrtf((float)c + 1.0f);  // +1 self-loop
    s[threadIdx.x] = c;
    __syncthreads();
    for (int o = 128; o > 0; o >>= 1) {
        if (threadIdx.x < o) s[threadIdx.x] += s[threadIdx.x + o];
        __syncthreads();
    }
    if (threadIdx.x == 0) bsum[blockIdx.x] = s[0];
}

__global__ __launch_bounds__(256) void scan_top(const int* __restrict__ bsum, int* __restrict__ bsumS) {
    __shared__ int s[256];
    int t = threadIdx.x;
    int v = (t < SCAN_BLOCKS) ? bsum[t] : 0;
    s[t] = v;
    __syncthreads();
    for (int o = 1; o < 256; o <<= 1) {
        int tmp = (t >= o) ? s[t - o] : 0;
        __syncthreads();
        s[t] += tmp;
        __syncthreads();
    }
    if (t < SCAN_BLOCKS) bsumS[t] = s[t] - v;
}

__global__ __launch_bounds__(256) void scan_final(const int* __restrict__ cnt, const int* __restrict__ bsumS,
                                                  int* __restrict__ row_ptr) {
    __shared__ int s[256];
    int t = threadIdx.x;
    int i = blockIdx.x * 256 + t;
    int v = (i < NNODES) ? cnt[i] : 0;
    s[t] = v;
    __syncthreads();
    for (int o = 1; o < 256; o <<= 1) {
        int tmp = (t >= o) ? s[t - o] : 0;
        __syncthreads();
        s[t] += tmp;
        __syncthreads();
    }
    if (i < NNODES) row_ptr[i] = s[t] - v + bsumS[blockIdx.x];
    if (i == 0) row_ptr[NNODES] = NEDGES;
}

// ---------------- fused fp32->bf16 converts: x (6250 blocks) + W1/W2/W3 transposes (640 blocks) ----------------
__global__ __launch_bounds__(256) void convert_all(const float* __restrict__ x,
                                                   const float* __restrict__ W1, const float* __restrict__ W2,
                                                   const float* __restrict__ W3, u16* __restrict__ xb,
                                                   u16* __restrict__ W1t, u16* __restrict__ W2t,
                                                   u16* __restrict__ W3t) {
    int bid = blockIdx.x;
    if (bid < 6250) {
        int i = bid * 256 + threadIdx.x;  // 1,600,000 float4 units exactly
        float4 v = ((const float4*)x)[i];
        ushort4 o;
        o.x = f2b(v.x); o.y = f2b(v.y); o.z = f2b(v.z); o.w = f2b(v.w);
        ((ushort4*)xb)[i] = o;
    } else {
        int idx = (bid - 6250) * 256 + threadIdx.x;  // 163840 = 32768 + 65536 + 65536
        if (idx < 32768) {
            int k = idx >> 8, n = idx & 255;
            W1t[n * 128 + k] = f2b(W1[idx]);
        } else if (idx < 98304) {
            int j = idx - 32768;
            int k = j >> 8, n = j & 255;
            W2t[n * 256 + k] = f2b(W2[j]);
        } else {
            int j = idx - 98304;
            int k = j >> 8, n = j & 255;
            W3t[n * 256 + k] = f2b(W3[j]);
        }
    }
}

// ---------------- aggregation ----------------
// out[v] = dv * ( dv*h[v] + sum_e w[e]*h[src[e]] ),  pw[e] = bf16(dinv[src])<<16 | src
template <int F>
__global__ __launch_bounds__(256) void agg_kernel(const u16* __restrict__ h,
                                                  const int* __restrict__ row_ptr,
                                                  const u32* __restrict__ pw,
                                                  const float* __restrict__ dinv,
                                                  u16* __restrict__ outb) {
    constexpr int VEC = F / 64;  // 2 (F=128) or 4 (F=256) bf16 per lane
    int lane = threadIdx.x & 63;
    int v = __builtin_amdgcn_readfirstlane((int)(blockIdx.x * 4 + (threadIdx.x >> 6)));
    const size_t lo = (size_t)lane * VEC;

    const int e0 = row_ptr[v], e1 = row_ptr[v + 1];
    float dv = dinv[v];
    float acc[VEC];
    {
        const u16* p = h + (size_t)v * F + lo;
        if constexpr (VEC == 4) {
            ushort4 t = *(const ushort4*)p;
            acc[0] = dv * b2f(t.x); acc[1] = dv * b2f(t.y); acc[2] = dv * b2f(t.z); acc[3] = dv * b2f(t.w);
        } else {
            ushort2 t = *(const ushort2*)p;
            acc[0] = dv * b2f(t.x); acc[1] = dv * b2f(t.y);
        }
    }
    // unconditional clamped unroll-8: all loads always issue (max MLP), OOB slots get w=0
    for (int e = e0; e < e1; e += 8) {
        u32 pk[8];
#pragma unroll
        for (int u = 0; u < 8; ++u) {
            int idx = e + u;
            pk[u] = pw[idx < e1 ? idx : e1 - 1];  // safe: loop entered only if e1 > e0
        }
        int   c[8];
        float w[8];
#pragma unroll
        for (int u = 0; u < 8; ++u) {
            c[u] = (int)(pk[u] & 0xFFFFu);
            w[u] = (e + u < e1) ? b2f((u16)(pk[u] >> 16)) : 0.0f;
        }
        if constexpr (VEC == 4) {
            ushort4 r[8];
#pragma unroll
            for (int u = 0; u < 8; ++u)
                r[u] = *(const ushort4*)(h + (size_t)c[u] * F + lo);
#pragma unroll
            for (int u = 0; u < 8; ++u) {
                acc[0] += w[u] * b2f(r[u].x);
                acc[1] += w[u] * b2f(r[u].y);
                acc[2] += w[u] * b2f(r[u].z);
                acc[3] += w[u] * b2f(r[u].w);
            }
        } else {
            ushort2 r[8];
#pragma unroll
            for (int u = 0; u < 8; ++u)
                r[u] = *(const ushort2*)(h + (size_t)c[u] * F + lo);
#pragma unroll
            for (int u = 0; u < 8; ++u) {
                acc[0] += w[u] * b2f(r[u].x);
                acc[1] += w[u] * b2f(r[u].y);
            }
        }
    }
    u16* o = outb + (size_t)v * F + lo;
    if constexpr (VEC == 4) {
        ushort4 t;
        t.x = f2b(dv * acc[0]); t.y = f2b(dv * acc[1]); t.z = f2b(dv * acc[2]); t.w = f2b(dv * acc[3]);
        *(ushort4*)o = t;
    } else {
        ushort2 t;
        t.x = f2b(dv * acc[0]); t.y = f2b(dv * acc[1]);
        *(ushort2*)o = t;
    }
}

// ---------------- bf16 MFMA GEMM: out[M x 256] = A[M x KT] @ W[KT x 256] + b ----------------
template <int KT, bool RELU, bool OUT_BF16>
__global__ __launch_bounds__(256) void gemm_mfma(const u16* __restrict__ A, const u16* __restrict__ Wt,
                                                 const float* __restrict__ bias, void* __restrict__ outp,
                                                 int M) {
    constexpr int BM = 128, BN = 128, BK = 32;
    __shared__ __align__(16) u16 As[BM * BK];
    __shared__ __align__(16) u16 Bs[BN * BK];
    const int tid = threadIdx.x;
    const int lane = tid & 63, wid = tid >> 6;
    const int l15 = lane & 15, lhi = lane >> 4;
    const int m0 = blockIdx.x * BM, n0 = blockIdx.y * BN;
    const int wr = (wid >> 1) * 64, wc = (wid & 1) * 64;

    f32x4 acc[4][4] = {};

    const int sr = tid >> 1;        // staging row 0..127
    const int sc2 = (tid & 1) * 2;  // staging chunk base (0 or 2)

    for (int k0 = 0; k0 < KT; k0 += BK) {
        uint4 av0, av1, bv0, bv1;
        int ar = m0 + sr;
        if (ar < M) {
            const uint4* ap = (const uint4*)(A + (size_t)ar * KT + k0 + sc2 * 8);
            av0 = ap[0]; av1 = ap[1];
        } else {
            av0 = make_uint4(0, 0, 0, 0); av1 = av0;
        }
        const uint4* bp = (const uint4*)(Wt + (size_t)(n0 + sr) * KT + k0 + sc2 * 8);
        bv0 = bp[0]; bv1 = bp[1];

        __syncthreads();
        *(uint4*)&As[sr * BK + ((sc2 ^ (sr & 3)) * 8)]       = av0;
        *(uint4*)&As[sr * BK + (((sc2 + 1) ^ (sr & 3)) * 8)] = av1;
        *(uint4*)&Bs[sr * BK + ((sc2 ^ (sr & 3)) * 8)]       = bv0;
        *(uint4*)&Bs[sr * BK + (((sc2 + 1) ^ (sr & 3)) * 8)] = bv1;
        __syncthreads();

        s16x8 af[4], bfr[4];
#pragma unroll
        for (int m = 0; m < 4; ++m) {
            int r = wr + m * 16 + l15;
            af[m] = *(const s16x8*)&As[r * BK + ((lhi ^ (r & 3)) * 8)];
        }
#pragma unroll
        for (int n = 0; n < 4; ++n) {
            int r = wc + n * 16 + l15;
            bfr[n] = *(const s16x8*)&Bs[r * BK + ((lhi ^ (r & 3)) * 8)];
        }
#pragma unroll
        for (int m = 0; m < 4; ++m)
#pragma unroll
            for (int n = 0; n < 4; ++n)
                acc[m][n] = __builtin_amdgcn_mfma_f32_16x16x32_bf16(af[m], bfr[n], acc[m][n], 0, 0, 0);
    }

    // epilogue: C/D layout col = lane&15, row = (lane>>4)*4 + reg
#pragma unroll
    for (int n = 0; n < 4; ++n) {
        int gcol = n0 + wc + n * 16 + l15;
        float bb = bias[gcol];
#pragma unroll
        for (int m = 0; m < 4; ++m) {
            int gr0 = m0 + wr + m * 16 + lhi * 4;
#pragma unroll
            for (int r = 0; r < 4; ++r) {
                int gr = gr0 + r;
                if (gr >= M) continue;
                float vv = acc[m][n][r] + bb;
                if (RELU) vv = vv > 0.f ? vv : 0.f;
                if (OUT_BF16)
                    ((u16*)outp)[(size_t)gr * 256 + gcol] = f2b(vv);
                else
                    ((float*)outp)[(size_t)gr * 256 + gcol] = vv;
            }
        }
    }
}

// ---------------- launch ----------------
extern "C" void kernel_launch(void* const* d_in, const int* in_sizes, int n_in,
                              void* d_out, int out_size, void* d_ws, size_t ws_size,
                              hipStream_t stream) {
    const float* x  = (const float*)d_in[0];
    const void* edges = d_in[1];
    const float* W1 = (const float*)d_in[2];
    const float* b1 = (const float*)d_in[3];
    const float* W2 = (const float*)d_in[4];
    const float* b2 = (const float*)d_in[5];
    const float* W3 = (const float*)d_in[6];
    const float* b3 = (const float*)d_in[7];
    float* out = (float*)d_out;

    char* ws = (char*)d_ws;
    float* dinv   = (float*)(ws + OFF_DINV);
    int*   rowptr = (int*)(ws + OFF_ROWPTR);
    int*   cnt    = (int*)(ws + OFF_CNT);
    int*   bsum   = (int*)(ws + OFF_BSUM);
    int*   bsumS  = (int*)(ws + OFF_BSUMS);
    int*   cmat   = (int*)(ws + OFF_CMAT);
    u32*   pairs  = (u32*)(ws + OFF_PAIRS);
    u32*   pw     = (u32*)(ws + OFF_PW);
    u16*   xb     = (u16*)(ws + OFF_XB);
    u16*   hb     = (u16*)(ws + OFF_HB);
    u16*   aggb   = (u16*)(ws + OFF_AGGB);
    u16*   W1t    = (u16*)(ws + OFF_W1T);
    u16*   W2t    = (u16*)(ws + OFF_W2T);
    u16*   W3t    = (u16*)(ws + OFF_W3T);

    hipMemsetAsync(cnt, 0, NNODES * sizeof(int), stream);

    // histogram + degree count (fused, per-block dtype detect)
    hist_kernel<<<NBLK, 256, 0, stream>>>(edges, cnt, cmat);

    // exclusive scan -> row_ptr (+dinv)
    scan_reduce<<<SCAN_BLOCKS, 256, 0, stream>>>(cnt, bsum, dinv);
    scan_top<<<1, 256, 0, stream>>>(bsum, bsumS);
    scan_final<<<SCAN_BLOCKS, 256, 0, stream>>>(cnt, bsumS, rowptr);

    // per-(bucket,block) offsets; scatter; per-node ranking -> packed pw
    offset_kernel<<<NB2, 256, 0, stream>>>(rowptr, cmat);
    scatter_kernel<<<NBLK, 256, 0, stream>>>(edges, cmat, pairs);
    phase2_fill<<<NB2, 256, 0, stream>>>(pairs, rowptr, dinv, pw);

    // bf16 converts (x + all weight transposes, one launch)
    convert_all<<<6890, 256, 0, stream>>>(x, W1, W2, W3, xb, W1t, W2t, W3t);

    const int AGG_GRID = NNODES / 4;  // 12500
    dim3 ggrid((NNODES + 127) / 128, 2);

    // layer 1
    agg_kernel<F_IN><<<AGG_GRID, 256, 0, stream>>>(xb, rowptr, pw, dinv, aggb);
    gemm_mfma<F_IN, true, true><<<ggrid, 256, 0, stream>>>(aggb, W1t, b1, hb, NNODES);

    // layer 2
    agg_kernel<F_HID><<<AGG_GRID, 256, 0, stream>>>(hb, rowptr, pw, dinv, aggb);
    gemm_mfma<F_HID, true, true><<<ggrid, 256, 0, stream>>>(aggb, W2t, b2, hb, NNODES);

    // layer 3
    agg_kernel<F_HID><<<AGG_GRID, 256, 0, stream>>>(hb, rowptr, pw, dinv, aggb);
    gemm_mfma<F_HID, false, false><<<ggrid, 256, 0, stream>>>(aggb, W3t, b3, out, NNODES);
}

// Round 7
// 283.361 us; speedup vs baseline: 1.6424x; 1.1168x over previous
//
#include <hip/hip_runtime.h>
#include <hip/hip_bf16.h>

#define NNODES 50000
#define NEDGES 800000
#define F_IN 128
#define F_HID 256

using u16 = unsigned short;
using u32 = unsigned int;
using f32x4 = __attribute__((ext_vector_type(4))) float;
using s16x8 = __attribute__((ext_vector_type(8))) short;

constexpr int B2SHIFT = 9;                         // 512 nodes per coarse bucket
constexpr int NB2 = (NNODES + 511) >> 9;           // 98
constexpr int NBLK = 256;                          // scatter blocks
constexpr int EPB = NEDGES / NBLK;                 // 3125 edges per block (exact)

// ---------------- workspace layout (bytes) ----------------
constexpr size_t OFF_DINV   = 0;          // 200192
constexpr size_t OFF_ROWPTR = 200192;     // 200192
constexpr size_t OFF_CMAT   = 400384;     // 100352 (98*256*4)
constexpr size_t OFF_BTOT   = 500736;     // 1024
constexpr size_t OFF_BBASE  = 501760;     // 1024
constexpr size_t OFF_PAIRS  = 502784;     // 3200000 (800000 u32)
constexpr size_t OFF_PW     = 3702784;    // 3200000 (800000 u32 packed w|src)
constexpr size_t OFF_XB     = 6902784;    // 12800000 (50000x128 bf16)
constexpr size_t OFF_HB     = 19702784;   // 25600000 (50000x256 bf16)
constexpr size_t OFF_AGGB   = 45302784;   // 25600000
constexpr size_t OFF_W1T    = 70902784;   // 65536
constexpr size_t OFF_W2T    = 70968320;   // 131072
constexpr size_t OFF_W3T    = 71099392;   // 131072
// total ~71.2 MB

static __device__ __forceinline__ float b2f(u16 u) {
    union { unsigned int i; float f; } v;
    v.i = ((unsigned int)u) << 16;
    return v.f;
}
static __device__ __forceinline__ u16 f2b(float f) {
    __hip_bfloat16 h = __float2bfloat16(f);  // round-to-nearest
    return __builtin_bit_cast(u16, h);
}

// per-block edge-dtype detect: true => int64 layout.
static __device__ __forceinline__ bool detect_wide(const void* raw) {
    __shared__ int bad;
    if (threadIdx.x == 0) bad = 0;
    __syncthreads();
    unsigned long long v = ((const unsigned long long*)raw)[threadIdx.x & 255];
    if (v >= (unsigned long long)NNODES) atomicAdd(&bad, 1);
    __syncthreads();
    return bad == 0;
}

// ---------------- CSR build, contention-free, no global degree pass ----------------
// A: per-block LDS histogram over 98 coarse buckets
__global__ __launch_bounds__(256) void hist_kernel(const void* __restrict__ raw, int* __restrict__ cmat) {
    const bool wide = detect_wide(raw);
    __shared__ int h[NB2];
    int t = threadIdx.x;
    if (t < NB2) h[t] = 0;
    __syncthreads();
    const int base = blockIdx.x * EPB;
    for (int i = t; i < EPB; i += 256) {
        int e = base + i;
        int d = wide ? (int)((const long long*)raw)[NEDGES + e] : ((const int*)raw)[NEDGES + e];
        atomicAdd(&h[d >> B2SHIFT], 1);
    }
    __syncthreads();
    if (t < NB2) cmat[t * NBLK + blockIdx.x] = h[t];
}

// B: per-bucket exclusive scan over the 256 block-counts (bucket-local); bucket total out
__global__ __launch_bounds__(256) void offset_kernel(int* __restrict__ cmat, int* __restrict__ btot) {
    __shared__ int s[256];
    int b = blockIdx.x;      // bucket
    int t = threadIdx.x;     // block slot
    int v = cmat[b * NBLK + t];
    s[t] = v;
    __syncthreads();
    for (int o = 1; o < 256; o <<= 1) {
        int tmp = (t >= o) ? s[t - o] : 0;
        __syncthreads();
        s[t] += tmp;
        __syncthreads();
    }
    cmat[b * NBLK + t] = s[t] - v;  // exclusive, bucket-local
    if (t == 255) btot[b] = s[255];
}

// C: exclusive scan of 98 bucket totals -> bucket bases
__global__ void bscan_kernel(const int* __restrict__ btot, int* __restrict__ bbase) {
    __shared__ int s[128];
    int t = threadIdx.x;  // 128 threads
    int v = (t < NB2) ? btot[t] : 0;
    s[t] = v;
    __syncthreads();
    for (int o = 1; o < 128; o <<= 1) {
        int tmp = (t >= o) ? s[t - o] : 0;
        __syncthreads();
        s[t] += tmp;
        __syncthreads();
    }
    if (t < NB2) bbase[t] = s[t] - v;
}

// D: scatter edges into exact bucket regions; cursors in LDS (block-private)
__global__ __launch_bounds__(256) void scatter_kernel(const void* __restrict__ raw,
                                                      const int* __restrict__ cmat,
                                                      const int* __restrict__ bbase,
                                                      u32* __restrict__ pairs) {
    const bool wide = detect_wide(raw);
    __shared__ int cur[NB2];
    int t = threadIdx.x;
    if (t < NB2) cur[t] = cmat[t * NBLK + blockIdx.x] + bbase[t];
    __syncthreads();
    const int base = blockIdx.x * EPB;
    for (int i = t; i < EPB; i += 256) {
        int e = base + i;
        int s, d;
        if (wide) {
            const long long* p = (const long long*)raw;
            s = (int)p[e];
            d = (int)p[NEDGES + e];
        } else {
            const int* p = (const int*)raw;
            s = p[e];
            d = p[NEDGES + e];
        }
        int pos = atomicAdd(&cur[d >> B2SHIFT], 1);
        pairs[pos] = ((u32)(d & 511) << 16) | (u32)s;  // src < 50000 < 2^16
    }
}

// E: per-bucket degree count (LDS) + 512-wide LDS scan -> row_ptr + dinv
__global__ __launch_bounds__(256) void phase2a(const u32* __restrict__ pairs,
                                               const int* __restrict__ bbase, const int* __restrict__ btot,
                                               int* __restrict__ row_ptr, float* __restrict__ dinv) {
    __shared__ int lcnt[512];
    __shared__ int ssc[512];
    int b = blockIdx.x, t = threadIdx.x;
    int n0 = b << B2SHIFT;
    lcnt[t] = 0; lcnt[t + 256] = 0;
    __syncthreads();
    int p0 = bbase[b], p1 = p0 + btot[b];
    for (int p = p0 + t; p < p1; p += 256)
        atomicAdd(&lcnt[pairs[p] >> 16], 1);
    __syncthreads();
    int c0 = lcnt[t], c1 = lcnt[t + 256];
    ssc[t] = c0; ssc[t + 256] = c1;
    __syncthreads();
    for (int o = 1; o < 512; o <<= 1) {
        int a0 = (t >= o) ? ssc[t - o] : 0;
        int a1 = ssc[t + 256 - o];  // t+256 >= o always (o <= 256)
        __syncthreads();
        ssc[t] += a0; ssc[t + 256] += a1;
        __syncthreads();
    }
    int na = n0 + t, nb = n0 + t + 256;
    if (na < NNODES) { row_ptr[na] = p0 + ssc[t] - c0;       dinv[na] = rsqrtf((float)c0 + 1.0f); }
    if (nb < NNODES) { row_ptr[nb] = p0 + ssc[t + 256] - c1; dinv[nb] = rsqrtf((float)c1 + 1.0f); }
    if (b == 0 && t == 0) row_ptr[NNODES] = NEDGES;
}

// F: per-bucket ranking -> packed (bf16(dinv[src])<<16 | src) stream
__global__ __launch_bounds__(256) void phase2b(const u32* __restrict__ pairs,
                                               const int* __restrict__ bbase, const int* __restrict__ btot,
                                               const int* __restrict__ row_ptr, const float* __restrict__ dinv,
                                               u32* __restrict__ pw) {
    __shared__ int lcur[512];
    int b = blockIdx.x, t = threadIdx.x;
    int n0 = b << B2SHIFT;
    int na = n0 + t, nb = n0 + t + 256;
    lcur[t]       = (na < NNODES) ? row_ptr[na] : NEDGES;
    lcur[t + 256] = (nb < NNODES) ? row_ptr[nb] : NEDGES;
    __syncthreads();
    int p0 = bbase[b], p1 = p0 + btot[b];
    for (int p = p0 + t; p < p1; p += 256) {
        u32 pk = pairs[p];
        int dl = (int)(pk >> 16);
        int src = (int)(pk & 0xFFFFu);
        int pos = atomicAdd(&lcur[dl], 1);
        pw[pos] = ((u32)f2b(dinv[src]) << 16) | (u32)src;  // dinv L2-resident
    }
}

// ---------------- fused fp32->bf16 converts: x (6250 blocks) + W transposes (640 blocks) ----------------
__global__ __launch_bounds__(256) void convert_all(const float* __restrict__ x,
                                                   const float* __restrict__ W1, const float* __restrict__ W2,
                                                   const float* __restrict__ W3, u16* __restrict__ xb,
                                                   u16* __restrict__ W1t, u16* __restrict__ W2t,
                                                   u16* __restrict__ W3t) {
    int bid = blockIdx.x;
    if (bid < 6250) {
        int i = bid * 256 + threadIdx.x;  // 1,600,000 float4 units exactly
        float4 v = ((const float4*)x)[i];
        ushort4 o;
        o.x = f2b(v.x); o.y = f2b(v.y); o.z = f2b(v.z); o.w = f2b(v.w);
        ((ushort4*)xb)[i] = o;
    } else {
        int idx = (bid - 6250) * 256 + threadIdx.x;  // 163840 = 32768 + 65536 + 65536
        if (idx < 32768) {
            int k = idx >> 8, n = idx & 255;
            W1t[n * 128 + k] = f2b(W1[idx]);
        } else if (idx < 98304) {
            int j = idx - 32768;
            int k = j >> 8, n = j & 255;
            W2t[n * 256 + k] = f2b(W2[j]);
        } else {
            int j = idx - 98304;
            int k = j >> 8, n = j & 255;
            W3t[n * 256 + k] = f2b(W3[j]);
        }
    }
}

// ---------------- aggregation ----------------
// out[v] = dv * ( dv*h[v] + sum_e w[e]*h[src[e]] ),  pw[e] = bf16(dinv[src])<<16 | src
// unroll-16, clamped loads (always issue; OOB slots get w=0) for max MLP
template <int F>
__global__ __launch_bounds__(256) void agg_kernel(const u16* __restrict__ h,
                                                  const int* __restrict__ row_ptr,
                                                  const u32* __restrict__ pw,
                                                  const float* __restrict__ dinv,
                                                  u16* __restrict__ outb) {
    constexpr int VEC = F / 64;  // 2 (F=128) or 4 (F=256) bf16 per lane
    int lane = threadIdx.x & 63;
    int v = __builtin_amdgcn_readfirstlane((int)(blockIdx.x * 4 + (threadIdx.x >> 6)));
    const size_t lo = (size_t)lane * VEC;

    const int e0 = row_ptr[v], e1 = row_ptr[v + 1];
    float dv = dinv[v];
    float acc[VEC];
    {
        const u16* p = h + (size_t)v * F + lo;
        if constexpr (VEC == 4) {
            ushort4 t = *(const ushort4*)p;
            acc[0] = dv * b2f(t.x); acc[1] = dv * b2f(t.y); acc[2] = dv * b2f(t.z); acc[3] = dv * b2f(t.w);
        } else {
            ushort2 t = *(const ushort2*)p;
            acc[0] = dv * b2f(t.x); acc[1] = dv * b2f(t.y);
        }
    }
    for (int e = e0; e < e1; e += 16) {
        u32 pk[16];
#pragma unroll
        for (int u = 0; u < 16; ++u) {
            int idx = e + u;
            pk[u] = pw[idx < e1 ? idx : e1 - 1];  // safe: loop entered only if e1 > e0
        }
        int   c[16];
        float w[16];
#pragma unroll
        for (int u = 0; u < 16; ++u) {
            c[u] = (int)(pk[u] & 0xFFFFu);
            w[u] = (e + u < e1) ? b2f((u16)(pk[u] >> 16)) : 0.0f;
        }
        if constexpr (VEC == 4) {
            ushort4 r[16];
#pragma unroll
            for (int u = 0; u < 16; ++u)
                r[u] = *(const ushort4*)(h + (size_t)c[u] * F + lo);
#pragma unroll
            for (int u = 0; u < 16; ++u) {
                acc[0] += w[u] * b2f(r[u].x);
                acc[1] += w[u] * b2f(r[u].y);
                acc[2] += w[u] * b2f(r[u].z);
                acc[3] += w[u] * b2f(r[u].w);
            }
        } else {
            ushort2 r[16];
#pragma unroll
            for (int u = 0; u < 16; ++u)
                r[u] = *(const ushort2*)(h + (size_t)c[u] * F + lo);
#pragma unroll
            for (int u = 0; u < 16; ++u) {
                acc[0] += w[u] * b2f(r[u].x);
                acc[1] += w[u] * b2f(r[u].y);
            }
        }
    }
    u16* o = outb + (size_t)v * F + lo;
    if constexpr (VEC == 4) {
        ushort4 t;
        t.x = f2b(dv * acc[0]); t.y = f2b(dv * acc[1]); t.z = f2b(dv * acc[2]); t.w = f2b(dv * acc[3]);
        *(ushort4*)o = t;
    } else {
        ushort2 t;
        t.x = f2b(dv * acc[0]); t.y = f2b(dv * acc[1]);
        *(ushort2*)o = t;
    }
}

// ---------------- bf16 MFMA GEMM: out[M x 256] = A[M x KT] @ W[KT x 256] + b ----------------
template <int KT, bool RELU, bool OUT_BF16>
__global__ __launch_bounds__(256) void gemm_mfma(const u16* __restrict__ A, const u16* __restrict__ Wt,
                                                 const float* __restrict__ bias, void* __restrict__ outp,
                                                 int M) {
    constexpr int BM = 128, BN = 128, BK = 32;
    __shared__ __align__(16) u16 As[BM * BK];
    __shared__ __align__(16) u16 Bs[BN * BK];
    const int tid = threadIdx.x;
    const int lane = tid & 63, wid = tid >> 6;
    const int l15 = lane & 15, lhi = lane >> 4;
    const int m0 = blockIdx.x * BM, n0 = blockIdx.y * BN;
    const int wr = (wid >> 1) * 64, wc = (wid & 1) * 64;

    f32x4 acc[4][4] = {};

    const int sr = tid >> 1;        // staging row 0..127
    const int sc2 = (tid & 1) * 2;  // staging chunk base (0 or 2)

    for (int k0 = 0; k0 < KT; k0 += BK) {
        uint4 av0, av1, bv0, bv1;
        int ar = m0 + sr;
        if (ar < M) {
            const uint4* ap = (const uint4*)(A + (size_t)ar * KT + k0 + sc2 * 8);
            av0 = ap[0]; av1 = ap[1];
        } else {
            av0 = make_uint4(0, 0, 0, 0); av1 = av0;
        }
        const uint4* bp = (const uint4*)(Wt + (size_t)(n0 + sr) * KT + k0 + sc2 * 8);
        bv0 = bp[0]; bv1 = bp[1];

        __syncthreads();
        *(uint4*)&As[sr * BK + ((sc2 ^ (sr & 3)) * 8)]       = av0;
        *(uint4*)&As[sr * BK + (((sc2 + 1) ^ (sr & 3)) * 8)] = av1;
        *(uint4*)&Bs[sr * BK + ((sc2 ^ (sr & 3)) * 8)]       = bv0;
        *(uint4*)&Bs[sr * BK + (((sc2 + 1) ^ (sr & 3)) * 8)] = bv1;
        __syncthreads();

        s16x8 af[4], bfr[4];
#pragma unroll
        for (int m = 0; m < 4; ++m) {
            int r = wr + m * 16 + l15;
            af[m] = *(const s16x8*)&As[r * BK + ((lhi ^ (r & 3)) * 8)];
        }
#pragma unroll
        for (int n = 0; n < 4; ++n) {
            int r = wc + n * 16 + l15;
            bfr[n] = *(const s16x8*)&Bs[r * BK + ((lhi ^ (r & 3)) * 8)];
        }
#pragma unroll
        for (int m = 0; m < 4; ++m)
#pragma unroll
            for (int n = 0; n < 4; ++n)
                acc[m][n] = __builtin_amdgcn_mfma_f32_16x16x32_bf16(af[m], bfr[n], acc[m][n], 0, 0, 0);
    }

    // epilogue: C/D layout col = lane&15, row = (lane>>4)*4 + reg
#pragma unroll
    for (int n = 0; n < 4; ++n) {
        int gcol = n0 + wc + n * 16 + l15;
        float bb = bias[gcol];
#pragma unroll
        for (int m = 0; m < 4; ++m) {
            int gr0 = m0 + wr + m * 16 + lhi * 4;
#pragma unroll
            for (int r = 0; r < 4; ++r) {
                int gr = gr0 + r;
                if (gr >= M) continue;
                float vv = acc[m][n][r] + bb;
                if (RELU) vv = vv > 0.f ? vv : 0.f;
                if (OUT_BF16)
                    ((u16*)outp)[(size_t)gr * 256 + gcol] = f2b(vv);
                else
                    ((float*)outp)[(size_t)gr * 256 + gcol] = vv;
            }
        }
    }
}

// ---------------- launch ----------------
extern "C" void kernel_launch(void* const* d_in, const int* in_sizes, int n_in,
                              void* d_out, int out_size, void* d_ws, size_t ws_size,
                              hipStream_t stream) {
    const float* x  = (const float*)d_in[0];
    const void* edges = d_in[1];
    const float* W1 = (const float*)d_in[2];
    const float* b1 = (const float*)d_in[3];
    const float* W2 = (const float*)d_in[4];
    const float* b2 = (const float*)d_in[5];
    const float* W3 = (const float*)d_in[6];
    const float* b3 = (const float*)d_in[7];
    float* out = (float*)d_out;

    char* ws = (char*)d_ws;
    float* dinv   = (float*)(ws + OFF_DINV);
    int*   rowptr = (int*)(ws + OFF_ROWPTR);
    int*   cmat   = (int*)(ws + OFF_CMAT);
    int*   btot   = (int*)(ws + OFF_BTOT);
    int*   bbase  = (int*)(ws + OFF_BBASE);
    u32*   pairs  = (u32*)(ws + OFF_PAIRS);
    u32*   pw     = (u32*)(ws + OFF_PW);
    u16*   xb     = (u16*)(ws + OFF_XB);
    u16*   hb     = (u16*)(ws + OFF_HB);
    u16*   aggb   = (u16*)(ws + OFF_AGGB);
    u16*   W1t    = (u16*)(ws + OFF_W1T);
    u16*   W2t    = (u16*)(ws + OFF_W2T);
    u16*   W3t    = (u16*)(ws + OFF_W3T);

    // CSR build: hist -> offsets -> bucket bases -> scatter -> row_ptr/dinv -> pw
    hist_kernel<<<NBLK, 256, 0, stream>>>(edges, cmat);
    offset_kernel<<<NB2, 256, 0, stream>>>(cmat, btot);
    bscan_kernel<<<1, 128, 0, stream>>>(btot, bbase);
    scatter_kernel<<<NBLK, 256, 0, stream>>>(edges, cmat, bbase, pairs);
    phase2a<<<NB2, 256, 0, stream>>>(pairs, bbase, btot, rowptr, dinv);
    phase2b<<<NB2, 256, 0, stream>>>(pairs, bbase, btot, rowptr, dinv, pw);

    // bf16 converts (x + all weight transposes, one launch)
    convert_all<<<6890, 256, 0, stream>>>(x, W1, W2, W3, xb, W1t, W2t, W3t);

    const int AGG_GRID = NNODES / 4;  // 12500
    dim3 ggrid((NNODES + 127) / 128, 2);

    // layer 1
    agg_kernel<F_IN><<<AGG_GRID, 256, 0, stream>>>(xb, rowptr, pw, dinv, aggb);
    gemm_mfma<F_IN, true, true><<<ggrid, 256, 0, stream>>>(aggb, W1t, b1, hb, NNODES);

    // layer 2
    agg_kernel<F_HID><<<AGG_GRID, 256, 0, stream>>>(hb, rowptr, pw, dinv, aggb);
    gemm_mfma<F_HID, true, true><<<ggrid, 256, 0, stream>>>(aggb, W2t, b2, hb, NNODES);

    // layer 3
    agg_kernel<F_HID><<<AGG_GRID, 256, 0, stream>>>(hb, rowptr, pw, dinv, aggb);
    gemm_mfma<F_HID, false, false><<<ggrid, 256, 0, stream>>>(aggb, W3t, b3, out, NNODES);
}